// Round 7
// baseline (103.170 us; speedup 1.0000x reference)
//
#include <hip/hip_runtime.h>
#include <math.h>

#define NROW 768
#define DIM  128

constexpr int H0c  = 256;
constexpr int H1c  = 362;
constexpr int HP1c = 368;   // H1 padded; pad columns are exact zeros

// Workspace layout (float offsets). ~3.9 MB total.
// hx stored in PANEL layout: [HP/4][768][4] so the pair kernel's per-thread
// read hx[i, hb..hb+3] is one coalesced float4 (lane = i).
constexpr int HX0_OFF  = 0;         // [64][768][4]
constexpr int HYB0_OFF = 196608;    // [768][256]   hy0 + b1_0 (row-major)
constexpr int HX1_OFF  = 393216;    // [92][768][4]
constexpr int HYB1_OFF = 675840;    // [768][368]   hy1 + b1_1 (row-major)
constexpr int PMAX_OFF = 958464;    // [2][768][2]  per-iq-half row max
constexpr int PSUM_OFF = 961536;    // [2][768][2]
constexpr int DIAG_OFF = 964608;    // [2][768]     s_diag
constexpr int UHP_OFF  = 966144;    // [2][2][768]  u partials (est, ht)

// ---------------------------------------------------------------------------
// prep: four projections (256 thr, 4h x 4rows, 16 fma chains / thread).
// (unchanged from round 6 — passing, ~10 us)
// ---------------------------------------------------------------------------
template <int M, int HT>
__device__ __forceinline__ void prep_body(
    const float* __restrict__ s0, const float* __restrict__ s1, const float* __restrict__ s2,
    const float* __restrict__ W1_0, const float* __restrict__ b1_0, const float* __restrict__ W2_0,
    const float* __restrict__ W1_1, const float* __restrict__ b1_1, const float* __restrict__ W2_1,
    float* __restrict__ ws, float* __restrict__ xs) {
  constexpr int K     = (M == 2) ? 256 : 128;
  constexpr int HREAL = (M <= 1) ? H0c : H1c;
  constexpr int HP    = (M <= 1) ? H0c : HP1c;
  constexpr int WOFF  = (M == 1) ? 128 : (M == 3) ? 256 : 0;
  constexpr int HACT  = (M <= 1) ? 256 : 184;
  constexpr int EST   = (M <= 1) ? 0 : 1;

  const float* __restrict__ W    = (M <= 1) ? W1_0 : W1_1;
  const float* __restrict__ bias = (M == 1) ? b1_0 : (M == 3) ? b1_1 : nullptr;
  const float* __restrict__ W2   = (M <= 1) ? W2_0 : W2_1;

  const int i0  = blockIdx.x * 16;
  const int tx  = threadIdx.x;            // 0..63
  const int ty  = threadIdx.y;            // 0..3
  const int tid = ty * 64 + tx;

  {
    const float* __restrict__ sa = (M == 3) ? s2 : (M == 1) ? s1 : s0;
    constexpr int NF4 = 16 * (K / 4);
    for (int idx = tid; idx < NF4; idx += 256) {
      const int row = idx / (K / 4);
      const int c4  = (idx % (K / 4)) * 4;
      float4 v;
      if (M == 2 && c4 >= DIM)
        v = *(const float4*)&s1[(i0 + row) * DIM + (c4 - DIM)];
      else
        v = *(const float4*)&sa[(i0 + row) * DIM + c4];
      *(float4*)&xs[row * K + c4] = v;
    }
  }
  __syncthreads();

  const bool own   = (tx * 4 < HACT);
  const int  h4    = HT * HACT + tx * 4;
  const bool fullw = (h4 + 4 <= HREAL);
  const int  h4c   = fullw ? h4 : (HREAL - 4);
  const int  r0    = ty * 4;
  float acc[4][4] = {};
  const float* __restrict__ Wb = W + WOFF * HREAL + h4c;

  for (int d = 0; d < K; d += 4) {
    float4 xv[4];
    #pragma unroll
    for (int r = 0; r < 4; ++r) xv[r] = *(const float4*)&xs[(r0 + r) * K + d];
    float4 wv[4];
    #pragma unroll
    for (int dd = 0; dd < 4; ++dd)
      wv[dd] = *(const float4*)&Wb[(d + dd) * HREAL];
    #pragma unroll
    for (int dd = 0; dd < 4; ++dd) {
      #pragma unroll
      for (int r = 0; r < 4; ++r) {
        const float xval = ((const float*)&xv[r])[dd];
        acc[r][0] = fmaf(xval, wv[dd].x, acc[r][0]);
        acc[r][1] = fmaf(xval, wv[dd].y, acc[r][1]);
        acc[r][2] = fmaf(xval, wv[dd].z, acc[r][2]);
        acc[r][3] = fmaf(xval, wv[dd].w, acc[r][3]);
      }
    }
  }

  if (M >= 2 && !fullw && h4 < HREAL) {
    #pragma unroll
    for (int r = 0; r < 4; ++r) {
      acc[r][0] = acc[r][2]; acc[r][1] = acc[r][3];
      acc[r][2] = 0.f;       acc[r][3] = 0.f;
    }
  }

  const bool ok0 = (h4 + 0 < HREAL), ok1 = (h4 + 1 < HREAL),
             ok2 = (h4 + 2 < HREAL), ok3 = (h4 + 3 < HREAL);

  float* __restrict__ outp = ws + ((M == 0) ? HX0_OFF : (M == 1) ? HYB0_OFF
                                 : (M == 2) ? HX1_OFF : HYB1_OFF);
  if (own && h4 < HP) {
    if ((M & 1) == 0) {
      const int pbase = (h4 >> 2) * (NROW * 4);
      #pragma unroll
      for (int r = 0; r < 4; ++r) {
        float4 v;
        v.x = ok0 ? acc[r][0] : 0.f;
        v.y = ok1 ? acc[r][1] : 0.f;
        v.z = ok2 ? acc[r][2] : 0.f;
        v.w = ok3 ? acc[r][3] : 0.f;
        *(float4*)&outp[pbase + (i0 + r0 + r) * 4] = v;
      }
    } else {
      float bv[4] = {0.f, 0.f, 0.f, 0.f};
      if (ok0) bv[0] = bias[h4 + 0];
      if (ok1) bv[1] = bias[h4 + 1];
      if (ok2) bv[2] = bias[h4 + 2];
      if (ok3) bv[3] = bias[h4 + 3];
      #pragma unroll
      for (int r = 0; r < 4; ++r) {
        float4 v;
        v.x = ok0 ? acc[r][0] + bv[0] : 0.f;
        v.y = ok1 ? acc[r][1] + bv[1] : 0.f;
        v.z = ok2 ? acc[r][2] + bv[2] : 0.f;
        v.w = ok3 ? acc[r][3] + bv[3] : 0.f;
        *(float4*)&outp[(i0 + r0 + r) * HP + h4] = v;
      }
    }
  }

  if ((M & 1) == 0) {
    float w2v[4];
    w2v[0] = (own && ok0) ? W2[h4 + 0] : 0.f;
    w2v[1] = (own && ok1) ? W2[h4 + 1] : 0.f;
    w2v[2] = (own && ok2) ? W2[h4 + 2] : 0.f;
    w2v[3] = (own && ok3) ? W2[h4 + 3] : 0.f;
    #pragma unroll
    for (int r = 0; r < 4; ++r) {
      float p = acc[r][0] * w2v[0] + acc[r][1] * w2v[1] +
                acc[r][2] * w2v[2] + acc[r][3] * w2v[3];
      #pragma unroll
      for (int off = 32; off > 0; off >>= 1) p += __shfl_xor(p, off);
      if (tx == 0)
        ws[UHP_OFF + EST * 1536 + HT * NROW + i0 + r0 + r] = p;
    }
  }
}

__global__ __launch_bounds__(256) void prep_kernel(
    const float* __restrict__ s0, const float* __restrict__ s1, const float* __restrict__ s2,
    const float* __restrict__ W1_0, const float* __restrict__ b1_0, const float* __restrict__ W2_0,
    const float* __restrict__ W1_1, const float* __restrict__ b1_1, const float* __restrict__ W2_1,
    float* __restrict__ ws) {
  __shared__ float xs[16 * 256];
  switch (blockIdx.y) {
    case 0: prep_body<0, 0>(s0, s1, s2, W1_0, b1_0, W2_0, W1_1, b1_1, W2_1, ws, xs); break;
    case 1: prep_body<1, 0>(s0, s1, s2, W1_0, b1_0, W2_0, W1_1, b1_1, W2_1, ws, xs); break;
    case 2: prep_body<2, 0>(s0, s1, s2, W1_0, b1_0, W2_0, W1_1, b1_1, W2_1, ws, xs); break;
    case 3: prep_body<2, 1>(s0, s1, s2, W1_0, b1_0, W2_0, W1_1, b1_1, W2_1, ws, xs); break;
    case 4: prep_body<3, 0>(s0, s1, s2, W1_0, b1_0, W2_0, W1_1, b1_1, W2_1, ws, xs); break;
    default: prep_body<3, 1>(s0, s1, s2, W1_0, b1_0, W2_0, W1_1, b1_1, W2_1, ws, xs); break;
  }
}

// ---------------------------------------------------------------------------
// pair: s[j,i] = 0.5*u_i + 0.5*sum_h w_h*|hx[i,h]+hyb[j,h]|; per-row partial
// max / sum-exp over an i-half (384 cols).
// Block = 128 thr (2 waves), thread: 3 i x 6 j = 18 acc.  Grid
// (128 jt, 2 iq, 2 est) = 512 blocks x 2 waves = 1024 waves = 4/CU = 1/SIMD
// EVEN; 2 blocks/CU mixes est0/est1 for balance.  launch_bounds(128,2)
// -> VGPR cap 256.  Ping-pong software pipeline: x (global/L2) and y
// (uniform LDS broadcast) quads loaded 2 phases (~550 VALU cyc) ahead.
// ---------------------------------------------------------------------------
template <int HP, int HREAL, bool TWO>
__device__ __forceinline__ void pair_body(
    const float* __restrict__ hx4, const float* __restrict__ hyb,
    const float* __restrict__ W2, const float* __restrict__ uhp,
    float* __restrict__ pmax, float* __restrict__ psum, float* __restrict__ sdiag,
    float* sh) {
  constexpr int NQ = HP / 4;
  float* ys   = sh;             // [6][HP]
  float* w2s  = sh + 6 * HP;    // [HP]
  float* redm = w2s + HP;       // [2][6]
  float* reds = redm + 12;      // [2][6]

  const int tid = threadIdx.x;          // 0..127
  const int j0  = blockIdx.x * 6;
  const int iq  = blockIdx.y;           // 0..1

  for (int idx = tid; idx < 6 * NQ; idx += 128) {
    const int row = idx / NQ;
    const int c4  = (idx % NQ) * 4;
    *(float4*)&ys[row * HP + c4] = *(const float4*)&hyb[(j0 + row) * HP + c4];
  }
  for (int q = tid; q < NQ; q += 128) {
    const int h = q * 4;
    float4 v;
    v.x = (h + 0 < HREAL) ? W2[h + 0] : 0.f;
    v.y = (h + 1 < HREAL) ? W2[h + 1] : 0.f;
    v.z = (h + 2 < HREAL) ? W2[h + 2] : 0.f;
    v.w = (h + 3 < HREAL) ? W2[h + 3] : 0.f;
    *(float4*)&w2s[h] = v;
  }
  __syncthreads();

  const int ia = iq * 384 + tid;        // three i's per thread
  const int ib = ia + 128;
  const int ic = ia + 256;
  float u[3];
  u[0] = uhp[ia]; u[1] = uhp[ib]; u[2] = uhp[ic];
  if (TWO) { u[0] += uhp[NROW + ia]; u[1] += uhp[NROW + ib]; u[2] += uhp[NROW + ic]; }
  u[0] *= 0.5f; u[1] *= 0.5f; u[2] *= 0.5f;

  float acc[6][3] = {};

  const float* xpa = hx4 + ia * 4;      // quad q lives at xpa + q*3072
  const float* xpb = hx4 + ib * 4;
  const float* xpc = hx4 + ic * 4;

  // ping-pong buffers (static names -> registers, no rotation moves)
  float4 xA0, xA1, xA2, xB0, xB1, xB2;
  float4 yA[6], yB[6], wA, wB;

  auto ldx = [&](int q, float4& x0, float4& x1, float4& x2) {
    x0 = *(const float4*)(xpa + q * (NROW * 4));
    x1 = *(const float4*)(xpb + q * (NROW * 4));
    x2 = *(const float4*)(xpc + q * (NROW * 4));
  };
  auto ldy = [&](int q, float4* y, float4& w) {
    const int hb = q * 4;
    #pragma unroll
    for (int r = 0; r < 6; ++r) y[r] = *(const float4*)&ys[r * HP + hb];
    w = *(const float4*)&w2s[hb];
  };
  auto compute = [&](const float4& x0, const float4& x1, const float4& x2,
                     const float4* y, const float4& w) {
    #pragma unroll
    for (int r = 0; r < 6; ++r) {
      const float4 yq = y[r];
      acc[r][0] = fmaf(fabsf(x0.x + yq.x), w.x, acc[r][0]);
      acc[r][0] = fmaf(fabsf(x0.y + yq.y), w.y, acc[r][0]);
      acc[r][0] = fmaf(fabsf(x0.z + yq.z), w.z, acc[r][0]);
      acc[r][0] = fmaf(fabsf(x0.w + yq.w), w.w, acc[r][0]);
      acc[r][1] = fmaf(fabsf(x1.x + yq.x), w.x, acc[r][1]);
      acc[r][1] = fmaf(fabsf(x1.y + yq.y), w.y, acc[r][1]);
      acc[r][1] = fmaf(fabsf(x1.z + yq.z), w.z, acc[r][1]);
      acc[r][1] = fmaf(fabsf(x1.w + yq.w), w.w, acc[r][1]);
      acc[r][2] = fmaf(fabsf(x2.x + yq.x), w.x, acc[r][2]);
      acc[r][2] = fmaf(fabsf(x2.y + yq.y), w.y, acc[r][2]);
      acc[r][2] = fmaf(fabsf(x2.z + yq.z), w.z, acc[r][2]);
      acc[r][2] = fmaf(fabsf(x2.w + yq.w), w.w, acc[r][2]);
    }
  };

  ldx(0, xA0, xA1, xA2); ldy(0, yA, wA);
  ldx(1, xB0, xB1, xB2); ldy(1, yB, wB);

  for (int q = 0; q < NQ; q += 2) {
    const int qa = (q + 2 < NQ) ? q + 2 : NQ - 1;   // clamped prefetch idx
    const int qb = (q + 3 < NQ) ? q + 3 : NQ - 1;
    compute(xA0, xA1, xA2, yA, wA);
    ldx(qa, xA0, xA1, xA2); ldy(qa, yA, wA);
    compute(xB0, xB1, xB2, yB, wB);
    ldx(qb, xB0, xB1, xB2); ldy(qb, yB, wB);
  }

  float s[6][3];
  #pragma unroll
  for (int r = 0; r < 6; ++r) {
    s[r][0] = fmaf(0.5f, acc[r][0], u[0]);
    s[r][1] = fmaf(0.5f, acc[r][1], u[1]);
    s[r][2] = fmaf(0.5f, acc[r][2], u[2]);
  }

  // diagonal s (t0 path; v_j and b2 cancel against lse)
  #pragma unroll
  for (int r = 0; r < 6; ++r) {
    const int jr    = j0 + r;
    const int local = jr - iq * 384;
    if (local >= 0 && local < 384 && tid == (local & 127)) {
      const int slot = local >> 7;
      float v = (slot == 0) ? s[r][0] : (slot == 1) ? s[r][1] : s[r][2];
      sdiag[jr] = v;
    }
  }

  const int lane = tid & 63;
  const int wv   = tid >> 6;   // 0..1

  float M[6];
  #pragma unroll
  for (int r = 0; r < 6; ++r) {
    float mm = fmaxf(fmaxf(s[r][0], s[r][1]), s[r][2]);
    #pragma unroll
    for (int off = 32; off > 0; off >>= 1) mm = fmaxf(mm, __shfl_xor(mm, off));
    M[r] = mm;
  }
  if (lane == 0) {
    #pragma unroll
    for (int r = 0; r < 6; ++r) redm[wv * 6 + r] = M[r];
  }
  __syncthreads();
  #pragma unroll
  for (int r = 0; r < 6; ++r) M[r] = fmaxf(redm[r], redm[6 + r]);

  #pragma unroll
  for (int r = 0; r < 6; ++r) {
    float e = __expf(s[r][0] - M[r]) + __expf(s[r][1] - M[r]) + __expf(s[r][2] - M[r]);
    #pragma unroll
    for (int off = 32; off > 0; off >>= 1) e += __shfl_xor(e, off);
    if (lane == 0) reds[wv * 6 + r] = e;
  }
  __syncthreads();
  if (tid < 6) {
    pmax[(j0 + tid) * 2 + iq] = fmaxf(redm[tid], redm[6 + tid]);
    psum[(j0 + tid) * 2 + iq] = reds[tid] + reds[6 + tid];
  }
}

__global__ __launch_bounds__(128, 2) void pair_kernel(
    float* __restrict__ ws, const float* __restrict__ W2_0, const float* __restrict__ W2_1) {
  __shared__ float sh[6 * HP1c + HP1c + 24];
  if (blockIdx.z == 0)
    pair_body<H0c, H0c, false>(ws + HX0_OFF, ws + HYB0_OFF, W2_0, ws + UHP_OFF,
                               ws + PMAX_OFF, ws + PSUM_OFF, ws + DIAG_OFF, sh);
  else
    pair_body<HP1c, H1c, true>(ws + HX1_OFF, ws + HYB1_OFF, W2_1, ws + UHP_OFF + 1536,
                               ws + PMAX_OFF + 1536, ws + PSUM_OFF + 1536,
                               ws + DIAG_OFF + NROW, sh);
}

// ---------------------------------------------------------------------------
// final: merge 2 i-half partials -> lse per row; sum (s_diag - lse); scalar.
// ---------------------------------------------------------------------------
__global__ __launch_bounds__(1024) void final_kernel(
    const float* __restrict__ ws, float* __restrict__ out) {
  __shared__ float red[1024];
  const int t = threadIdx.x;
  float val = 0.f;
  if (t < NROW) {
    #pragma unroll
    for (int est = 0; est < 2; ++est) {
      const float* pm = ws + PMAX_OFF + est * 1536 + t * 2;
      const float* ps = ws + PSUM_OFF + est * 1536 + t * 2;
      float M = fmaxf(pm[0], pm[1]);
      float S = ps[0] * __expf(pm[0] - M) + ps[1] * __expf(pm[1] - M);
      float lse = M + logf(S);
      val += ws[DIAG_OFF + est * NROW + t] - lse;
    }
  }
  red[t] = val;
  __syncthreads();
  for (int sdown = 512; sdown > 0; sdown >>= 1) {
    if (t < sdown) red[t] += red[t + sdown];
    __syncthreads();
  }
  if (t == 0) out[0] = red[0] * (1.0f / (float)NROW) + 2.0f * logf((float)NROW);
}

// ---------------------------------------------------------------------------
extern "C" void kernel_launch(void* const* d_in, const int* in_sizes, int n_in,
                              void* d_out, int out_size, void* d_ws, size_t ws_size,
                              hipStream_t stream) {
  const float* s0   = (const float*)d_in[0];
  const float* s1   = (const float*)d_in[1];
  const float* s2   = (const float*)d_in[2];
  const float* W1_0 = (const float*)d_in[3];
  const float* b1_0 = (const float*)d_in[4];
  const float* W2_0 = (const float*)d_in[5];
  const float* W1_1 = (const float*)d_in[7];
  const float* b1_1 = (const float*)d_in[8];
  const float* W2_1 = (const float*)d_in[9];
  float* ws  = (float*)d_ws;
  float* out = (float*)d_out;

  hipLaunchKernelGGL(prep_kernel, dim3(48, 6), dim3(64, 4), 0, stream,
                     s0, s1, s2, W1_0, b1_0, W2_0, W1_1, b1_1, W2_1, ws);
  hipLaunchKernelGGL(pair_kernel, dim3(128, 2, 2), dim3(128), 0, stream,
                     ws, W2_0, W2_1);
  hipLaunchKernelGGL(final_kernel, dim3(1), dim3(1024), 0, stream, ws, out);
}

// Round 8
// 60.278 us; speedup vs baseline: 1.7116x; 1.7116x over previous
//
#include <hip/hip_runtime.h>
#include <math.h>

#define NROW 768
#define DIM  128

constexpr int H0c  = 256;
constexpr int H1c  = 362;
constexpr int HP1c = 368;   // H1 padded; pad columns are exact zeros

// Workspace layout (float offsets). ~3.9 MB total.
// hx stored in PANEL layout: [HP/4][768][4] so the pair kernel's per-thread
// read hx[i, hb..hb+3] is one coalesced float4 (lane = i).
constexpr int HX0_OFF  = 0;         // [64][768][4]
constexpr int HYB0_OFF = 196608;    // [768][256]   hy0 + b1_0 (row-major)
constexpr int HX1_OFF  = 393216;    // [92][768][4]
constexpr int HYB1_OFF = 675840;    // [768][368]   hy1 + b1_1 (row-major)
constexpr int PMAX_OFF = 958464;    // [2][768][4]  per-iq row max (slots 0..2)
constexpr int PSUM_OFF = 964608;    // [2][768][4]
constexpr int DIAG_OFF = 970752;    // [2][768]     s_diag
constexpr int UHP_OFF  = 972288;    // [2][2][768]  u partials (est, ht)

// ---------------------------------------------------------------------------
// prep: four projections (256 thr, 4h x 4rows, 16 fma chains / thread).
// (structure unchanged from round 6 — passing, ~10-12 us)
// ---------------------------------------------------------------------------
template <int M, int HT>
__device__ __forceinline__ void prep_body(
    const float* __restrict__ s0, const float* __restrict__ s1, const float* __restrict__ s2,
    const float* __restrict__ W1_0, const float* __restrict__ b1_0, const float* __restrict__ W2_0,
    const float* __restrict__ W1_1, const float* __restrict__ b1_1, const float* __restrict__ W2_1,
    float* __restrict__ ws, float* __restrict__ xs) {
  constexpr int K     = (M == 2) ? 256 : 128;
  constexpr int HREAL = (M <= 1) ? H0c : H1c;
  constexpr int HP    = (M <= 1) ? H0c : HP1c;
  constexpr int WOFF  = (M == 1) ? 128 : (M == 3) ? 256 : 0;
  constexpr int HACT  = (M <= 1) ? 256 : 184;
  constexpr int EST   = (M <= 1) ? 0 : 1;

  const float* __restrict__ W    = (M <= 1) ? W1_0 : W1_1;
  const float* __restrict__ bias = (M == 1) ? b1_0 : (M == 3) ? b1_1 : nullptr;
  const float* __restrict__ W2   = (M <= 1) ? W2_0 : W2_1;

  const int i0  = blockIdx.x * 16;
  const int tx  = threadIdx.x;            // 0..63
  const int ty  = threadIdx.y;            // 0..3
  const int tid = ty * 64 + tx;

  {
    const float* __restrict__ sa = (M == 3) ? s2 : (M == 1) ? s1 : s0;
    constexpr int NF4 = 16 * (K / 4);
    for (int idx = tid; idx < NF4; idx += 256) {
      const int row = idx / (K / 4);
      const int c4  = (idx % (K / 4)) * 4;
      float4 v;
      if (M == 2 && c4 >= DIM)
        v = *(const float4*)&s1[(i0 + row) * DIM + (c4 - DIM)];
      else
        v = *(const float4*)&sa[(i0 + row) * DIM + c4];
      *(float4*)&xs[row * K + c4] = v;
    }
  }
  __syncthreads();

  const bool own   = (tx * 4 < HACT);
  const int  h4    = HT * HACT + tx * 4;
  const bool fullw = (h4 + 4 <= HREAL);
  const int  h4c   = fullw ? h4 : (HREAL - 4);
  const int  r0    = ty * 4;
  float acc[4][4] = {};
  const float* __restrict__ Wb = W + WOFF * HREAL + h4c;

  for (int d = 0; d < K; d += 4) {
    float4 xv[4];
    #pragma unroll
    for (int r = 0; r < 4; ++r) xv[r] = *(const float4*)&xs[(r0 + r) * K + d];
    float4 wv[4];
    #pragma unroll
    for (int dd = 0; dd < 4; ++dd)
      wv[dd] = *(const float4*)&Wb[(d + dd) * HREAL];
    #pragma unroll
    for (int dd = 0; dd < 4; ++dd) {
      #pragma unroll
      for (int r = 0; r < 4; ++r) {
        const float xval = ((const float*)&xv[r])[dd];
        acc[r][0] = fmaf(xval, wv[dd].x, acc[r][0]);
        acc[r][1] = fmaf(xval, wv[dd].y, acc[r][1]);
        acc[r][2] = fmaf(xval, wv[dd].z, acc[r][2]);
        acc[r][3] = fmaf(xval, wv[dd].w, acc[r][3]);
      }
    }
  }

  if (M >= 2 && !fullw && h4 < HREAL) {
    #pragma unroll
    for (int r = 0; r < 4; ++r) {
      acc[r][0] = acc[r][2]; acc[r][1] = acc[r][3];
      acc[r][2] = 0.f;       acc[r][3] = 0.f;
    }
  }

  const bool ok0 = (h4 + 0 < HREAL), ok1 = (h4 + 1 < HREAL),
             ok2 = (h4 + 2 < HREAL), ok3 = (h4 + 3 < HREAL);

  float* __restrict__ outp = ws + ((M == 0) ? HX0_OFF : (M == 1) ? HYB0_OFF
                                 : (M == 2) ? HX1_OFF : HYB1_OFF);
  if (own && h4 < HP) {
    if ((M & 1) == 0) {
      const int pbase = (h4 >> 2) * (NROW * 4);
      #pragma unroll
      for (int r = 0; r < 4; ++r) {
        float4 v;
        v.x = ok0 ? acc[r][0] : 0.f;
        v.y = ok1 ? acc[r][1] : 0.f;
        v.z = ok2 ? acc[r][2] : 0.f;
        v.w = ok3 ? acc[r][3] : 0.f;
        *(float4*)&outp[pbase + (i0 + r0 + r) * 4] = v;
      }
    } else {
      float bv[4] = {0.f, 0.f, 0.f, 0.f};
      if (ok0) bv[0] = bias[h4 + 0];
      if (ok1) bv[1] = bias[h4 + 1];
      if (ok2) bv[2] = bias[h4 + 2];
      if (ok3) bv[3] = bias[h4 + 3];
      #pragma unroll
      for (int r = 0; r < 4; ++r) {
        float4 v;
        v.x = ok0 ? acc[r][0] + bv[0] : 0.f;
        v.y = ok1 ? acc[r][1] + bv[1] : 0.f;
        v.z = ok2 ? acc[r][2] + bv[2] : 0.f;
        v.w = ok3 ? acc[r][3] + bv[3] : 0.f;
        *(float4*)&outp[(i0 + r0 + r) * HP + h4] = v;
      }
    }
  }

  if ((M & 1) == 0) {
    float w2v[4];
    w2v[0] = (own && ok0) ? W2[h4 + 0] : 0.f;
    w2v[1] = (own && ok1) ? W2[h4 + 1] : 0.f;
    w2v[2] = (own && ok2) ? W2[h4 + 2] : 0.f;
    w2v[3] = (own && ok3) ? W2[h4 + 3] : 0.f;
    #pragma unroll
    for (int r = 0; r < 4; ++r) {
      float p = acc[r][0] * w2v[0] + acc[r][1] * w2v[1] +
                acc[r][2] * w2v[2] + acc[r][3] * w2v[3];
      #pragma unroll
      for (int off = 32; off > 0; off >>= 1) p += __shfl_xor(p, off);
      if (tx == 0)
        ws[UHP_OFF + EST * 1536 + HT * NROW + i0 + r0 + r] = p;
    }
  }
}

__global__ __launch_bounds__(256) void prep_kernel(
    const float* __restrict__ s0, const float* __restrict__ s1, const float* __restrict__ s2,
    const float* __restrict__ W1_0, const float* __restrict__ b1_0, const float* __restrict__ W2_0,
    const float* __restrict__ W1_1, const float* __restrict__ b1_1, const float* __restrict__ W2_1,
    float* __restrict__ ws) {
  __shared__ float xs[16 * 256];
  switch (blockIdx.y) {
    case 0: prep_body<0, 0>(s0, s1, s2, W1_0, b1_0, W2_0, W1_1, b1_1, W2_1, ws, xs); break;
    case 1: prep_body<1, 0>(s0, s1, s2, W1_0, b1_0, W2_0, W1_1, b1_1, W2_1, ws, xs); break;
    case 2: prep_body<2, 0>(s0, s1, s2, W1_0, b1_0, W2_0, W1_1, b1_1, W2_1, ws, xs); break;
    case 3: prep_body<2, 1>(s0, s1, s2, W1_0, b1_0, W2_0, W1_1, b1_1, W2_1, ws, xs); break;
    case 4: prep_body<3, 0>(s0, s1, s2, W1_0, b1_0, W2_0, W1_1, b1_1, W2_1, ws, xs); break;
    default: prep_body<3, 1>(s0, s1, s2, W1_0, b1_0, W2_0, W1_1, b1_1, W2_1, ws, xs); break;
  }
}

// ---------------------------------------------------------------------------
// pair: round-2 structure EXACTLY (the measured-best launch shape: 256 thr,
// J=4 j-rows, I=1 i/thread, grid (192,3,2) = 1152 blocks = 4.5 blk/CU =
// 18 waves/CU = 4.5/SIMD), with only the inner loop swapped to the |z| form:
//   s[j,i] = 0.5*u_i + 0.5*sum_h w_h*|hx[i,h]+hyb[j,h]|
// 2 VALU/elem (v_add_f32 + v_fma_f32 with |.| source modifier).
// TLP (4.5 waves/SIMD) hides L2/LDS latency — rounds 5-7 proved static
// pipelining at low occupancy cannot.
// ---------------------------------------------------------------------------
template <int HP, int HREAL, bool TWO>
__device__ __forceinline__ void pair_body(
    const float* __restrict__ hx4, const float* __restrict__ hyb,
    const float* __restrict__ W2, const float* __restrict__ uhp,
    float* __restrict__ pmax, float* __restrict__ psum, float* __restrict__ sdiag,
    float* sh) {
  constexpr int NQ = HP / 4;
  float* ys   = sh;             // [4][HP]
  float* w2s  = sh + 4 * HP;    // [HP]
  float* redm = w2s + HP;       // [4 waves][4 rows]
  float* reds = redm + 16;      // [4 waves][4 rows]

  const int tid = threadIdx.x;          // 0..255
  const int j0  = blockIdx.x * 4;
  const int iq  = blockIdx.y;           // 0..2
  const int i   = iq * 256 + tid;

  for (int idx = tid; idx < 4 * NQ; idx += 256) {
    const int row = idx / NQ;
    const int c4  = (idx % NQ) * 4;
    *(float4*)&ys[row * HP + c4] = *(const float4*)&hyb[(j0 + row) * HP + c4];
  }
  for (int q = tid; q < NQ; q += 256) {
    const int h = q * 4;
    float4 v;
    v.x = (h + 0 < HREAL) ? W2[h + 0] : 0.f;
    v.y = (h + 1 < HREAL) ? W2[h + 1] : 0.f;
    v.z = (h + 2 < HREAL) ? W2[h + 2] : 0.f;
    v.w = (h + 3 < HREAL) ? W2[h + 3] : 0.f;
    *(float4*)&w2s[h] = v;
  }
  __syncthreads();

  float u = uhp[i];
  if (TWO) u += uhp[NROW + i];
  u *= 0.5f;

  float acc[4] = {0.f, 0.f, 0.f, 0.f};
  const float* xp = hx4 + i * 4;
  #pragma unroll 2
  for (int hb = 0; hb < HP; hb += 4, xp += NROW * 4) {
    const float4 a = *(const float4*)xp;
    const float4 w = *(const float4*)&w2s[hb];
    #pragma unroll
    for (int r = 0; r < 4; ++r) {
      const float4 y = *(const float4*)&ys[r * HP + hb];
      acc[r] = fmaf(fabsf(a.x + y.x), w.x, acc[r]);
      acc[r] = fmaf(fabsf(a.y + y.y), w.y, acc[r]);
      acc[r] = fmaf(fabsf(a.z + y.z), w.z, acc[r]);
      acc[r] = fmaf(fabsf(a.w + y.w), w.w, acc[r]);
    }
  }

  float s[4];
  #pragma unroll
  for (int r = 0; r < 4; ++r) s[r] = fmaf(0.5f, acc[r], u);

  // diagonal s (t0 path; v_j and b2 cancel against lse)
  const int dj = i - j0;
  if (dj == 0) sdiag[i] = s[0];
  else if (dj == 1) sdiag[i] = s[1];
  else if (dj == 2) sdiag[i] = s[2];
  else if (dj == 3) sdiag[i] = s[3];

  const int lane = tid & 63;
  const int wv   = tid >> 6;   // 0..3

  float M[4];
  #pragma unroll
  for (int r = 0; r < 4; ++r) {
    float mm = s[r];
    #pragma unroll
    for (int off = 32; off > 0; off >>= 1) mm = fmaxf(mm, __shfl_xor(mm, off));
    M[r] = mm;
  }
  if (lane == 0) {
    #pragma unroll
    for (int r = 0; r < 4; ++r) redm[wv * 4 + r] = M[r];
  }
  __syncthreads();
  #pragma unroll
  for (int r = 0; r < 4; ++r)
    M[r] = fmaxf(fmaxf(redm[r], redm[4 + r]), fmaxf(redm[8 + r], redm[12 + r]));

  #pragma unroll
  for (int r = 0; r < 4; ++r) {
    float e = __expf(s[r] - M[r]);
    #pragma unroll
    for (int off = 32; off > 0; off >>= 1) e += __shfl_xor(e, off);
    if (lane == 0) reds[wv * 4 + r] = e;
  }
  __syncthreads();
  if (tid < 4) {
    const float m = fmaxf(fmaxf(redm[tid], redm[4 + tid]),
                          fmaxf(redm[8 + tid], redm[12 + tid]));
    const float sm = reds[tid] + reds[4 + tid] + reds[8 + tid] + reds[12 + tid];
    pmax[(j0 + tid) * 4 + iq] = m;
    psum[(j0 + tid) * 4 + iq] = sm;
  }
}

__global__ __launch_bounds__(256) void pair_kernel(
    float* __restrict__ ws, const float* __restrict__ W2_0, const float* __restrict__ W2_1) {
  __shared__ float sh[4 * HP1c + HP1c + 32];
  if (blockIdx.z == 0)
    pair_body<H0c, H0c, false>(ws + HX0_OFF, ws + HYB0_OFF, W2_0, ws + UHP_OFF,
                               ws + PMAX_OFF, ws + PSUM_OFF, ws + DIAG_OFF, sh);
  else
    pair_body<HP1c, H1c, true>(ws + HX1_OFF, ws + HYB1_OFF, W2_1, ws + UHP_OFF + 1536,
                               ws + PMAX_OFF + 3072, ws + PSUM_OFF + 3072,
                               ws + DIAG_OFF + NROW, sh);
}

// ---------------------------------------------------------------------------
// final: merge 3 i-quarter partials -> lse per row; sum (s_diag - lse).
// ---------------------------------------------------------------------------
__global__ __launch_bounds__(1024) void final_kernel(
    const float* __restrict__ ws, float* __restrict__ out) {
  __shared__ float red[1024];
  const int t = threadIdx.x;
  float val = 0.f;
  if (t < NROW) {
    #pragma unroll
    for (int est = 0; est < 2; ++est) {
      const float* pm = ws + PMAX_OFF + est * 3072 + t * 4;
      const float* ps = ws + PSUM_OFF + est * 3072 + t * 4;
      float M = fmaxf(fmaxf(pm[0], pm[1]), pm[2]);
      float S = ps[0] * __expf(pm[0] - M) + ps[1] * __expf(pm[1] - M) +
                ps[2] * __expf(pm[2] - M);
      float lse = M + logf(S);
      val += ws[DIAG_OFF + est * NROW + t] - lse;
    }
  }
  red[t] = val;
  __syncthreads();
  for (int sdown = 512; sdown > 0; sdown >>= 1) {
    if (t < sdown) red[t] += red[t + sdown];
    __syncthreads();
  }
  if (t == 0) out[0] = red[0] * (1.0f / (float)NROW) + 2.0f * logf((float)NROW);
}

// ---------------------------------------------------------------------------
extern "C" void kernel_launch(void* const* d_in, const int* in_sizes, int n_in,
                              void* d_out, int out_size, void* d_ws, size_t ws_size,
                              hipStream_t stream) {
  const float* s0   = (const float*)d_in[0];
  const float* s1   = (const float*)d_in[1];
  const float* s2   = (const float*)d_in[2];
  const float* W1_0 = (const float*)d_in[3];
  const float* b1_0 = (const float*)d_in[4];
  const float* W2_0 = (const float*)d_in[5];
  const float* W1_1 = (const float*)d_in[7];
  const float* b1_1 = (const float*)d_in[8];
  const float* W2_1 = (const float*)d_in[9];
  float* ws  = (float*)d_ws;
  float* out = (float*)d_out;

  hipLaunchKernelGGL(prep_kernel, dim3(48, 6), dim3(64, 4), 0, stream,
                     s0, s1, s2, W1_0, b1_0, W2_0, W1_1, b1_1, W2_1, ws);
  hipLaunchKernelGGL(pair_kernel, dim3(192, 3, 2), dim3(256), 0, stream,
                     ws, W2_0, W2_1);
  hipLaunchKernelGGL(final_kernel, dim3(1), dim3(1024), 0, stream, ws, out);
}